// Round 20
// baseline (336.511 us; speedup 1.0000x reference)
//
#include <hip/hip_runtime.h>
#include <stdint.h>

#define BS_T   16384
#define XDIM   4096
#define KDIM   512
#define NKEYS  4096
#define KTOP   16

typedef _Float16 half8  __attribute__((ext_vector_type(8)));
typedef _Float16 half4  __attribute__((ext_vector_type(4)));
typedef float    floatx4 __attribute__((ext_vector_type(4)));

// async global->LDS, 16B per lane; LDS dest is wave-uniform base + lane*16
__device__ static inline void gload_lds16(const void* g, void* l) {
  __builtin_amdgcn_global_load_lds(
      (const __attribute__((address_space(1))) uint32_t*)(uintptr_t)g,
      (__attribute__((address_space(3))) uint32_t*)(uint32_t)(uintptr_t)l,
      16, 0, 0);
}

#define SBAR() __builtin_amdgcn_sched_barrier(0)
#define FULL_BAR() do { __builtin_amdgcn_sched_barrier(0); \
                        __builtin_amdgcn_s_barrier(); \
                        __builtin_amdgcn_sched_barrier(0); } while (0)

// ---------------- fp32 -> fp16 convert (vectorized, grid-stride) ----------------
__global__ __launch_bounds__(256) void cvt_f32_f16_v(const float* __restrict__ in,
                                                     _Float16* __restrict__ out, int n8) {
  int stride = gridDim.x * 256;
  for (int i = blockIdx.x * 256 + threadIdx.x; i < n8; i += stride) {
    float4 v0 = ((const float4*)in)[2 * i];
    float4 v1 = ((const float4*)in)[2 * i + 1];
    half8 h = { (_Float16)v0.x, (_Float16)v0.y, (_Float16)v0.z, (_Float16)v0.w,
                (_Float16)v1.x, (_Float16)v1.y, (_Float16)v1.z, (_Float16)v1.w };
    ((half8*)out)[i] = h;
  }
}

// ---------------- GEMM1 v11 (unchanged from R19) ----------------
__global__ __launch_bounds__(512, 1)
void gemm1_pipe(const float* __restrict__ X, const _Float16* __restrict__ Wh,
                const float* __restrict__ bias, _Float16* __restrict__ Q) {
  __shared__ __align__(16) _Float16 ldsA[2][64 * 64];    // 2 x 8 KB
  __shared__ __align__(16) _Float16 ldsB[2][512 * 64];   // 2 x 64 KB

  const int tid  = threadIdx.x;
  const int lane = tid & 63;
  const int wid  = tid >> 6;            // 0..7
  const int rowBase = blockIdx.x * 64;
  const int rot  = (blockIdx.x * 29) & 63;   // bijective k-tile rotation
  const int wc  = wid * 64;
  const int l15 = lane & 15;
  const int q4  = lane >> 4;
  const int sub   = lane >> 3;
  const int gslot = (lane & 7) ^ sub;

  auto KT = [&](int t) { return ((t + rot) & 63) * 64; };

  // A staging remap: f = tid + j*512; row = f>>4; 16B slot s = f&15 (row-contig)
  const int r0 = tid >> 4,          s0 = tid & 15;
  const int r1 = (tid + 512) >> 4,  s1 = (tid + 512) & 15;
  const float* aSrc0 = X + (size_t)(rowBase + r0) * XDIM + s0 * 4;
  const float* aSrc1 = X + (size_t)(rowBase + r1) * XDIM + s1 * 4;
  const int aoff0 = r0 * 128 + (((s0 >> 1) * 16) ^ ((r0 & 7) << 4)) + (s0 & 1) * 8;
  const int aoff1 = r1 * 128 + (((s1 >> 1) * 16) ^ ((r1 & 7) << 4)) + (s1 & 1) * 8;

  const _Float16* const bSrc = Wh + (size_t)(wc + sub) * XDIM + gslot * 8;

  auto stageB = [&](int kt, int buf) {
    char* bd = (char*)&ldsB[buf][0] + wid * 8192;
    #pragma unroll
    for (int i = 0; i < 8; ++i)
      gload_lds16(bSrc + (size_t)i * 8 * XDIM + kt, bd + i * 1024);
  };
  auto writeA = [&](int buf, float4 v0, float4 v1) {
    half4 h0 = { (_Float16)v0.x, (_Float16)v0.y, (_Float16)v0.z, (_Float16)v0.w };
    half4 h1 = { (_Float16)v1.x, (_Float16)v1.y, (_Float16)v1.z, (_Float16)v1.w };
    *(half4*)((char*)&ldsA[buf][0] + aoff0) = h0;
    *(half4*)((char*)&ldsA[buf][0] + aoff1) = h1;
  };
  auto ld8 = [&](const char* base, int row, int s) {
    return *(const half8*)(base + row * 128 + ((s * 16) ^ ((row & 7) << 4)));
  };

  floatx4 acc[4][4];
  #pragma unroll
  for (int m = 0; m < 4; ++m)
    #pragma unroll
    for (int n = 0; n < 4; ++n)
      acc[m][n] = (floatx4)0.0f;

  // ---- prologue (k-tiles KT(0), KT(1)) ----
  float4 p0  = *(const float4*)(aSrc0 + KT(0));
  float4 p1  = *(const float4*)(aSrc1 + KT(0));
  float4 aw0 = *(const float4*)(aSrc0 + KT(1));
  float4 aw1 = *(const float4*)(aSrc1 + KT(1));
  stageB(KT(0), 0);
  stageB(KT(1), 1);
  writeA(0, p0, p1);                                    // compiler waits p loads
  asm volatile("s_waitcnt lgkmcnt(0)" ::: "memory");
  asm volatile("s_waitcnt vmcnt(8)" ::: "memory");      // drain aw + B(0); B(1) flies
  FULL_BAR();

  #pragma unroll 2
  for (int t = 0; t < 64; ++t) {
    const int cu = t & 1;
    const char* bA = (const char*)&ldsA[cu][0];
    const char* bB = (const char*)&ldsB[cu][0];

    half8 a[4][2], b[4][2];
    #pragma unroll
    for (int m = 0; m < 4; ++m)
      #pragma unroll
      for (int kk = 0; kk < 2; ++kk)
        a[m][kk] = ld8(bA, m * 16 + l15, kk * 4 + q4);
    #pragma unroll
    for (int n = 0; n < 4; ++n)
      #pragma unroll
      for (int kk = 0; kk < 2; ++kk)
        b[n][kk] = ld8(bB, wc + n * 16 + l15, kk * 4 + q4);
    float4 nl0, nl1;
    if (t < 62) {
      nl0 = *(const float4*)(aSrc0 + KT(t + 2));
      nl1 = *(const float4*)(aSrc1 + KT(t + 2));
    }
    asm volatile("s_waitcnt lgkmcnt(0)" ::: "memory");
    __builtin_amdgcn_sched_barrier(0);
    if (t < 62) stageB(KT(t + 2), cu);
    __builtin_amdgcn_sched_barrier(0);

    __builtin_amdgcn_s_setprio(1);
    #pragma unroll
    for (int m = 0; m < 4; ++m)
      #pragma unroll
      for (int n = 0; n < 4; ++n)
        #pragma unroll
        for (int kk = 0; kk < 2; ++kk)
          acc[m][n] = __builtin_amdgcn_mfma_f32_16x16x32_f16(a[m][kk], b[n][kk], acc[m][n], 0, 0, 0);
    __builtin_amdgcn_s_setprio(0);

    if (t < 63) writeA(cu ^ 1, aw0, aw1);
    asm volatile("s_waitcnt lgkmcnt(0)" ::: "memory");
    __builtin_amdgcn_sched_barrier(0);
    if (t < 62)       asm volatile("s_waitcnt vmcnt(10)" ::: "memory");
    else if (t == 62) asm volatile("s_waitcnt vmcnt(0)"  ::: "memory");
    FULL_BAR();
    aw0 = nl0; aw1 = nl1;
  }

  // epilogue
  #pragma unroll
  for (int m = 0; m < 4; ++m) {
    #pragma unroll
    for (int n = 0; n < 4; ++n) {
      int col = wc + n * 16 + l15;
      float bv = bias[col];
      #pragma unroll
      for (int r = 0; r < 4; ++r) {
        int row = rowBase + m * 16 + q4 * 4 + r;
        Q[(size_t)row * KDIM + col] = (_Float16)(acc[m][n][r] + bv);
      }
    }
  }
}

// ---------------- GEMM2 pipelined + LDS-transposed coalesced C-write --------------
// Epilogue rework: the naive C-write is 128 scalar dword stores/thread (64B-run
// granule). Instead: stage 64-row chunks of the C tile in LDS (reusing ldsA, 64KB),
// then each wave stores ONE FULL 1KB contiguous row per instruction (float4/lane).
// 32 b128 stores/thread total. Values bit-identical.
__global__ __launch_bounds__(512, 2)
void gemm2_pipe(const _Float16* __restrict__ Aq, const _Float16* __restrict__ Bk,
                float* __restrict__ outp) {
  __shared__ __align__(16) _Float16 ldsA[2][256 * 64];   // 64 KB (reused by epilogue)
  __shared__ __align__(16) _Float16 ldsB[2][256 * 64];

  const int tid  = threadIdx.x;
  const int lane = tid & 63;
  const int wid  = tid >> 6;
  const int bid  = blockIdx.x;
  const int nCol = NKEYS / 256;
  const int rowBase = (bid / nCol) * 256;
  const int colBase = (bid % nCol) * 256;
  const int wm = wid >> 2;
  const int wn = wid & 3;
  const int l15 = lane & 15;
  const int q4  = lane >> 4;
  const int sub   = lane >> 3;
  const int gslot = (lane & 7) ^ sub;

  const _Float16* aSrc = Aq + (size_t)rowBase * KDIM;
  const _Float16* bSrc = Bk + (size_t)colBase * KDIM;

  auto stageHalf = [&](const _Float16* src, char* ldsbase, int kt, int h) {
    #pragma unroll
    for (int j = 0; j < 2; ++j) {
      int g = h * 16 + wid * 2 + j;
      gload_lds16(src + (size_t)(g * 8 + sub) * KDIM + kt + gslot * 8,
                  ldsbase + g * 1024);
    }
  };
  auto ld8 = [&](const char* base, int row, int s) {
    return *(const half8*)(base + row * 128 + ((s * 16) ^ ((row & 7) << 4)));
  };

  floatx4 acc[8][4];
  #pragma unroll
  for (int m = 0; m < 8; ++m)
    #pragma unroll
    for (int n = 0; n < 4; ++n)
      acc[m][n] = (floatx4)0.0f;

  stageHalf(aSrc, (char*)ldsA[0], 0, 0);
  stageHalf(aSrc, (char*)ldsA[0], 0, 1);
  stageHalf(bSrc, (char*)ldsB[0], 0, 0);
  stageHalf(bSrc, (char*)ldsB[0], 0, 1);
  stageHalf(aSrc, (char*)ldsA[1], 64, 0);
  stageHalf(aSrc, (char*)ldsA[1], 64, 1);
  stageHalf(bSrc, (char*)ldsB[1], 64, 0);
  stageHalf(bSrc, (char*)ldsB[1], 64, 1);
  asm volatile("s_waitcnt vmcnt(8)" ::: "memory");
  FULL_BAR();

  for (int t = 0; t < 8; ++t) {
    const char* bA = (const char*)ldsA[t & 1];
    const char* bB = (const char*)ldsB[t & 1];
    char* sA = (char*)ldsA[t & 1];
    char* sB = (char*)ldsB[t & 1];
    const int ktn = (t + 2) * 64;
    const bool st = (t < 6);

    half8 a[4][2], b[4][2];

    #pragma unroll
    for (int m = 0; m < 4; ++m)
      #pragma unroll
      for (int kk = 0; kk < 2; ++kk)
        a[m][kk] = ld8(bA, wm * 128 + m * 16 + l15, kk * 4 + q4);
    #pragma unroll
    for (int n = 0; n < 4; ++n)
      #pragma unroll
      for (int kk = 0; kk < 2; ++kk)
        b[n][kk] = ld8(bB, wn * 64 + n * 16 + l15, kk * 4 + q4);
    FULL_BAR();
    asm volatile("s_waitcnt lgkmcnt(0)" ::: "memory");
    __builtin_amdgcn_sched_barrier(0);
    __builtin_amdgcn_s_setprio(1);
    #pragma unroll
    for (int m = 0; m < 4; ++m)
      #pragma unroll
      for (int n = 0; n < 2; ++n)
        #pragma unroll
        for (int kk = 0; kk < 2; ++kk)
          acc[m][n] = __builtin_amdgcn_mfma_f32_16x16x32_f16(a[m][kk], b[n][kk], acc[m][n], 0, 0, 0);
    __builtin_amdgcn_s_setprio(0);
    FULL_BAR();

    if (st) stageHalf(bSrc, sB, ktn, 0);
    __builtin_amdgcn_sched_barrier(0);
    __builtin_amdgcn_s_setprio(1);
    #pragma unroll
    for (int m = 0; m < 4; ++m)
      #pragma unroll
      for (int n = 2; n < 4; ++n)
        #pragma unroll
        for (int kk = 0; kk < 2; ++kk)
          acc[m][n] = __builtin_amdgcn_mfma_f32_16x16x32_f16(a[m][kk], b[n][kk], acc[m][n], 0, 0, 0);
    __builtin_amdgcn_s_setprio(0);
    FULL_BAR();

    #pragma unroll
    for (int m = 0; m < 4; ++m)
      #pragma unroll
      for (int kk = 0; kk < 2; ++kk)
        a[m][kk] = ld8(bA, wm * 128 + (m + 4) * 16 + l15, kk * 4 + q4);
    if (st) stageHalf(bSrc, sB, ktn, 1);
    FULL_BAR();
    asm volatile("s_waitcnt lgkmcnt(0)" ::: "memory");
    __builtin_amdgcn_sched_barrier(0);
    __builtin_amdgcn_s_setprio(1);
    #pragma unroll
    for (int m = 0; m < 4; ++m)
      #pragma unroll
      for (int n = 0; n < 2; ++n)
        #pragma unroll
        for (int kk = 0; kk < 2; ++kk)
          acc[m + 4][n] = __builtin_amdgcn_mfma_f32_16x16x32_f16(a[m][kk], b[n][kk], acc[m + 4][n], 0, 0, 0);
    __builtin_amdgcn_s_setprio(0);
    FULL_BAR();

    if (st) { stageHalf(aSrc, sA, ktn, 0); stageHalf(aSrc, sA, ktn, 1); }
    __builtin_amdgcn_sched_barrier(0);
    __builtin_amdgcn_s_setprio(1);
    #pragma unroll
    for (int m = 0; m < 4; ++m)
      #pragma unroll
      for (int n = 2; n < 4; ++n)
        #pragma unroll
        for (int kk = 0; kk < 2; ++kk)
          acc[m + 4][n] = __builtin_amdgcn_mfma_f32_16x16x32_f16(a[m][kk], b[n][kk], acc[m + 4][n], 0, 0, 0);
    __builtin_amdgcn_s_setprio(0);
    __builtin_amdgcn_sched_barrier(0);
    if (t < 6)      asm volatile("s_waitcnt vmcnt(8)" ::: "memory");
    else if (t == 6) asm volatile("s_waitcnt vmcnt(0)" ::: "memory");
    FULL_BAR();
  }

  // ---- epilogue: 4 chunks of 64 rows; LDS transpose -> 1KB-contiguous row stores
  float* cbuf = (float*)&ldsA[0][0];    // 64 KB = 64 rows x 256 cols fp32
  #pragma unroll
  for (int c = 0; c < 4; ++c) {
    FULL_BAR();                          // prior chunk's reads done before overwrite
    if (wm == (c >> 1)) {
      const int mbase = (c & 1) * 4;
      #pragma unroll
      for (int mm = 0; mm < 4; ++mm) {
        const int rl0 = mbase * 16 + mm * 16 + q4 * 4 - (c & 1) * 64;  // 0..60
        #pragma unroll
        for (int n = 0; n < 4; ++n) {
          const int col = wn * 64 + n * 16 + l15;
          #pragma unroll
          for (int r = 0; r < 4; ++r)
            cbuf[(rl0 + r) * 256 + col] = acc[mbase + mm][n][r];
        }
      }
    }
    FULL_BAR();
    #pragma unroll
    for (int s2 = 0; s2 < 8; ++s2) {
      const int rl = s2 * 8 + wid;
      float4 v = *(const float4*)(cbuf + rl * 256 + lane * 4);
      *(float4*)(outp + (size_t)(rowBase + c * 64 + rl) * NKEYS + colBase + lane * 4) = v;
    }
  }
}

// ---------------- top-16 + scatter-softmax gates (radix-select) ----------------
__global__ __launch_bounds__(256) void topk_gates_kernel(const float* __restrict__ scores,
                                                         float* __restrict__ gates) {
  __shared__ uint32_t hist[4096];
  __shared__ uint32_t sA[256];
  __shared__ uint32_t av[16], ai[16];
  __shared__ uint32_t sk[KTOP], si[KTOP];
  __shared__ uint32_t cntA, cntC;
  __shared__ int s_p; __shared__ uint32_t s_above;
  __shared__ float gk[KTOP]; __shared__ float s_gother;

  const int tid  = threadIdx.x;
  const int lane = tid & 63;
  const int w    = tid >> 6;
  const float* srow = scores + (size_t)blockIdx.x * NKEYS;

  uint4 z4 = {0, 0, 0, 0};
  #pragma unroll
  for (int i = 0; i < 4; ++i) ((uint4*)hist)[tid + 256 * i] = z4;
  if (tid == 0) { cntA = 0; cntC = 0; }

  uint32_t key[16];
  const int base = (w << 10) + (lane << 4);
  {
    const float4* p4 = (const float4*)(srow + base);
    #pragma unroll
    for (int i = 0; i < 4; ++i) {
      float4 t = p4[i];
      float tv[4] = { t.x, t.y, t.z, t.w };
      #pragma unroll
      for (int c = 0; c < 4; ++c) {
        uint32_t u = __float_as_uint(tv[c]);
        key[i * 4 + c] = u ^ (uint32_t)(((int32_t)u >> 31) | 0x80000000);
      }
    }
  }
  __syncthreads();

  #pragma unroll
  for (int j = 0; j < 16; ++j) atomicAdd(&hist[key[j] >> 20], 1u);
  __syncthreads();

  uint32_t h[16];
  #pragma unroll
  for (int i = 0; i < 16; ++i) h[i] = hist[tid * 16 + i];
  uint32_t sfx[17]; sfx[16] = 0;
  #pragma unroll
  for (int i = 15; i >= 0; --i) sfx[i] = sfx[i + 1] + h[i];
  sA[tid] = sfx[0];
  __syncthreads();
  uint32_t s = sfx[0];
  #pragma unroll
  for (int off = 1; off < 256; off <<= 1) {
    uint32_t add = (tid + off < 256) ? sA[tid + off] : 0;
    __syncthreads();
    s += add; sA[tid] = s;
    __syncthreads();
  }
  const uint32_t exclHi = s - sfx[0];

  #pragma unroll
  for (int i = 0; i < 16; ++i) {
    uint32_t cg = exclHi + sfx[i + 1];
    if (cg < KTOP && cg + h[i] >= KTOP) { s_p = tid * 16 + i; s_above = cg; }
  }
  __syncthreads();
  const uint32_t p = (uint32_t)s_p;
  const uint32_t above = s_above;
  const uint32_t need = KTOP - above;

  uint32_t* ck = hist;
  uint32_t* ci = hist + 2048;
  #pragma unroll
  for (int j = 0; j < 16; ++j) {
    uint32_t b = key[j] >> 20;
    if (b >= p) {
      uint32_t idx = (uint32_t)(base + j);
      if (b > p) { uint32_t pos = atomicAdd(&cntA, 1u); av[pos] = key[j]; ai[pos] = idx; }
      else       { uint32_t pos = atomicAdd(&cntC, 1u); if (pos < 2048u) { ck[pos] = key[j]; ci[pos] = idx; } }
    }
  }
  __syncthreads();

  const uint32_t nA = cntA;
  if (tid < nA) { sk[tid] = av[tid]; si[tid] = ai[tid]; }

  if (w == 0) {
    const uint32_t nC = min(cntC, 2048u);
    for (uint32_t k = 0; k < need; ++k) {
      uint32_t bk = 0, bi = 0xFFFFFFFFu, bp = 0;
      for (uint32_t c = lane; c < nC; c += 64) {
        uint32_t kk = ck[c], ii = ci[c];
        if (kk > bk || (kk == bk && ii < bi)) { bk = kk; bi = ii; bp = c; }
      }
      #pragma unroll
      for (int off = 32; off >= 1; off >>= 1) {
        uint32_t ok = __shfl_down(bk, off);
        uint32_t oi = __shfl_down(bi, off);
        uint32_t op = __shfl_down(bp, off);
        if (ok > bk || (ok == bk && oi < bi)) { bk = ok; bi = oi; bp = op; }
      }
      bp = __shfl(bp, 0);
      if (lane == 0) { ck[bp] = 0; sk[nA + k] = bk; si[nA + k] = bi; }
    }
  }
  __syncthreads();

  if (tid == 0) {
    float f[KTOP]; float mx = 0.f;
    #pragma unroll
    for (int k = 0; k < KTOP; ++k) {
      uint32_t kk = sk[k];
      float fv = (kk & 0x80000000u) ? __uint_as_float(kk ^ 0x80000000u)
                                    : __uint_as_float(~kk);
      f[k] = fv; mx = fmaxf(mx, fv);
    }
    float eo = __expf(-mx);
    float Z = (float)(NKEYS - KTOP) * eo;
    float e[KTOP];
    #pragma unroll
    for (int k = 0; k < KTOP; ++k) { e[k] = __expf(f[k] - mx); Z += e[k]; }
    float inv = 1.f / Z;
    #pragma unroll
    for (int k = 0; k < KTOP; ++k) gk[k] = e[k] * inv;
    s_gother = eo * inv;
  }
  __syncthreads();

  float go = s_gother;
  floatx4 g4 = { go, go, go, go };
  float* grow = gates + (size_t)blockIdx.x * NKEYS;
  #pragma unroll
  for (int j = 0; j < 4; ++j)
    __builtin_nontemporal_store(g4, (floatx4*)grow + j * 256 + tid);
  __syncthreads();
  if (tid < KTOP) grow[si[tid]] = gk[tid];
}

extern "C" void kernel_launch(void* const* d_in, const int* in_sizes, int n_in,
                              void* d_out, int out_size, void* d_ws, size_t ws_size,
                              hipStream_t stream) {
  const float* x    = (const float*)d_in[0];
  const float* keys = (const float*)d_in[1];
  const float* W    = (const float*)d_in[2];
  const float* bias = (const float*)d_in[3];
  (void)in_sizes; (void)n_in; (void)out_size; (void)ws_size;

  float* gates  = (float*)d_out;
  float* scores = (float*)d_out + (size_t)BS_T * NKEYS;

  _Float16* W_h = (_Float16*)d_ws;                 // 4 MB
  _Float16* k_h = W_h + (size_t)KDIM * XDIM;       // 4 MB
  _Float16* q_h = k_h + (size_t)NKEYS * KDIM;      // 16 MB

  cvt_f32_f16_v<<<dim3(1024), dim3(256), 0, stream>>>(W, W_h, KDIM * XDIM / 8);
  cvt_f32_f16_v<<<dim3(1024), dim3(256), 0, stream>>>(keys, k_h, NKEYS * KDIM / 8);

  // query = x @ W^T + b -> q_h (fp16). v11: k-rotation + contiguous-A, grid 256
  gemm1_pipe<<<dim3(BS_T / 64), dim3(512), 0, stream>>>(x, W_h, bias, q_h);

  // scores = q @ keys^T -> fp32. 256x256, counted-vmcnt pipe + coalesced C-write
  gemm2_pipe<<<dim3((BS_T / 256) * (NKEYS / 256)), dim3(512), 0, stream>>>(
      q_h, k_h, scores);

  topk_gates_kernel<<<dim3(BS_T), dim3(256), 0, stream>>>(scores, gates);
}

// Round 21
// 331.653 us; speedup vs baseline: 1.0146x; 1.0146x over previous
//
#include <hip/hip_runtime.h>
#include <stdint.h>

#define BS_T   16384
#define XDIM   4096
#define KDIM   512
#define NKEYS  4096
#define KTOP   16

typedef _Float16 half8  __attribute__((ext_vector_type(8)));
typedef _Float16 half4  __attribute__((ext_vector_type(4)));
typedef float    floatx4 __attribute__((ext_vector_type(4)));

// async global->LDS, 16B per lane; LDS dest is wave-uniform base + lane*16
__device__ static inline void gload_lds16(const void* g, void* l) {
  __builtin_amdgcn_global_load_lds(
      (const __attribute__((address_space(1))) uint32_t*)(uintptr_t)g,
      (__attribute__((address_space(3))) uint32_t*)(uint32_t)(uintptr_t)l,
      16, 0, 0);
}

#define SBAR() __builtin_amdgcn_sched_barrier(0)
#define FULL_BAR() do { __builtin_amdgcn_sched_barrier(0); \
                        __builtin_amdgcn_s_barrier(); \
                        __builtin_amdgcn_sched_barrier(0); } while (0)

// ---------------- fp32 -> fp16 convert (vectorized, grid-stride) ----------------
__global__ __launch_bounds__(256) void cvt_f32_f16_v(const float* __restrict__ in,
                                                     _Float16* __restrict__ out, int n8) {
  int stride = gridDim.x * 256;
  for (int i = blockIdx.x * 256 + threadIdx.x; i < n8; i += stride) {
    float4 v0 = ((const float4*)in)[2 * i];
    float4 v1 = ((const float4*)in)[2 * i + 1];
    half8 h = { (_Float16)v0.x, (_Float16)v0.y, (_Float16)v0.z, (_Float16)v0.w,
                (_Float16)v1.x, (_Float16)v1.y, (_Float16)v1.z, (_Float16)v1.w };
    ((half8*)out)[i] = h;
  }
}

// ---------------- GEMM1 v11 (k-rotation + contiguous-A; best measured) -----------
__global__ __launch_bounds__(512, 1)
void gemm1_pipe(const float* __restrict__ X, const _Float16* __restrict__ Wh,
                const float* __restrict__ bias, _Float16* __restrict__ Q) {
  __shared__ __align__(16) _Float16 ldsA[2][64 * 64];    // 2 x 8 KB
  __shared__ __align__(16) _Float16 ldsB[2][512 * 64];   // 2 x 64 KB

  const int tid  = threadIdx.x;
  const int lane = tid & 63;
  const int wid  = tid >> 6;            // 0..7
  const int rowBase = blockIdx.x * 64;
  const int rot  = (blockIdx.x * 29) & 63;   // bijective k-tile rotation
  const int wc  = wid * 64;
  const int l15 = lane & 15;
  const int q4  = lane >> 4;
  const int sub   = lane >> 3;
  const int gslot = (lane & 7) ^ sub;

  auto KT = [&](int t) { return ((t + rot) & 63) * 64; };

  // A staging remap: f = tid + j*512; row = f>>4; 16B slot s = f&15 (row-contig)
  const int r0 = tid >> 4,          s0 = tid & 15;
  const int r1 = (tid + 512) >> 4,  s1 = (tid + 512) & 15;
  const float* aSrc0 = X + (size_t)(rowBase + r0) * XDIM + s0 * 4;
  const float* aSrc1 = X + (size_t)(rowBase + r1) * XDIM + s1 * 4;
  const int aoff0 = r0 * 128 + (((s0 >> 1) * 16) ^ ((r0 & 7) << 4)) + (s0 & 1) * 8;
  const int aoff1 = r1 * 128 + (((s1 >> 1) * 16) ^ ((r1 & 7) << 4)) + (s1 & 1) * 8;

  const _Float16* const bSrc = Wh + (size_t)(wc + sub) * XDIM + gslot * 8;

  auto stageB = [&](int kt, int buf) {
    char* bd = (char*)&ldsB[buf][0] + wid * 8192;
    #pragma unroll
    for (int i = 0; i < 8; ++i)
      gload_lds16(bSrc + (size_t)i * 8 * XDIM + kt, bd + i * 1024);
  };
  auto writeA = [&](int buf, float4 v0, float4 v1) {
    half4 h0 = { (_Float16)v0.x, (_Float16)v0.y, (_Float16)v0.z, (_Float16)v0.w };
    half4 h1 = { (_Float16)v1.x, (_Float16)v1.y, (_Float16)v1.z, (_Float16)v1.w };
    *(half4*)((char*)&ldsA[buf][0] + aoff0) = h0;
    *(half4*)((char*)&ldsA[buf][0] + aoff1) = h1;
  };
  auto ld8 = [&](const char* base, int row, int s) {
    return *(const half8*)(base + row * 128 + ((s * 16) ^ ((row & 7) << 4)));
  };

  floatx4 acc[4][4];
  #pragma unroll
  for (int m = 0; m < 4; ++m)
    #pragma unroll
    for (int n = 0; n < 4; ++n)
      acc[m][n] = (floatx4)0.0f;

  // ---- prologue (k-tiles KT(0), KT(1)) ----
  float4 p0  = *(const float4*)(aSrc0 + KT(0));
  float4 p1  = *(const float4*)(aSrc1 + KT(0));
  float4 aw0 = *(const float4*)(aSrc0 + KT(1));
  float4 aw1 = *(const float4*)(aSrc1 + KT(1));
  stageB(KT(0), 0);
  stageB(KT(1), 1);
  writeA(0, p0, p1);                                    // compiler waits p loads
  asm volatile("s_waitcnt lgkmcnt(0)" ::: "memory");
  asm volatile("s_waitcnt vmcnt(8)" ::: "memory");      // drain aw + B(0); B(1) flies
  FULL_BAR();

  #pragma unroll 2
  for (int t = 0; t < 64; ++t) {
    const int cu = t & 1;
    const char* bA = (const char*)&ldsA[cu][0];
    const char* bB = (const char*)&ldsB[cu][0];

    half8 a[4][2], b[4][2];
    #pragma unroll
    for (int m = 0; m < 4; ++m)
      #pragma unroll
      for (int kk = 0; kk < 2; ++kk)
        a[m][kk] = ld8(bA, m * 16 + l15, kk * 4 + q4);
    #pragma unroll
    for (int n = 0; n < 4; ++n)
      #pragma unroll
      for (int kk = 0; kk < 2; ++kk)
        b[n][kk] = ld8(bB, wc + n * 16 + l15, kk * 4 + q4);
    float4 nl0, nl1;
    if (t < 62) {
      nl0 = *(const float4*)(aSrc0 + KT(t + 2));
      nl1 = *(const float4*)(aSrc1 + KT(t + 2));
    }
    asm volatile("s_waitcnt lgkmcnt(0)" ::: "memory");
    __builtin_amdgcn_sched_barrier(0);
    if (t < 62) stageB(KT(t + 2), cu);
    __builtin_amdgcn_sched_barrier(0);

    __builtin_amdgcn_s_setprio(1);
    #pragma unroll
    for (int m = 0; m < 4; ++m)
      #pragma unroll
      for (int n = 0; n < 4; ++n)
        #pragma unroll
        for (int kk = 0; kk < 2; ++kk)
          acc[m][n] = __builtin_amdgcn_mfma_f32_16x16x32_f16(a[m][kk], b[n][kk], acc[m][n], 0, 0, 0);
    __builtin_amdgcn_s_setprio(0);

    if (t < 63) writeA(cu ^ 1, aw0, aw1);
    asm volatile("s_waitcnt lgkmcnt(0)" ::: "memory");
    __builtin_amdgcn_sched_barrier(0);
    if (t < 62)       asm volatile("s_waitcnt vmcnt(10)" ::: "memory");
    else if (t == 62) asm volatile("s_waitcnt vmcnt(0)"  ::: "memory");
    FULL_BAR();
    aw0 = nl0; aw1 = nl1;
  }

  // epilogue
  #pragma unroll
  for (int m = 0; m < 4; ++m) {
    #pragma unroll
    for (int n = 0; n < 4; ++n) {
      int col = wc + n * 16 + l15;
      float bv = bias[col];
      #pragma unroll
      for (int r = 0; r < 4; ++r) {
        int row = rowBase + m * 16 + q4 * 4 + r;
        Q[(size_t)row * KDIM + col] = (_Float16)(acc[m][n][r] + bv);
      }
    }
  }
}

// ---------------- GEMM2 pipelined (identity bid; direct C-store, R19 best) --------
__global__ __launch_bounds__(512, 2)
void gemm2_pipe(const _Float16* __restrict__ Aq, const _Float16* __restrict__ Bk,
                float* __restrict__ outp) {
  __shared__ __align__(16) _Float16 ldsA[2][256 * 64];
  __shared__ __align__(16) _Float16 ldsB[2][256 * 64];

  const int tid  = threadIdx.x;
  const int lane = tid & 63;
  const int wid  = tid >> 6;
  const int bid  = blockIdx.x;
  const int nCol = NKEYS / 256;
  const int rowBase = (bid / nCol) * 256;
  const int colBase = (bid % nCol) * 256;
  const int wm = wid >> 2;
  const int wn = wid & 3;
  const int l15 = lane & 15;
  const int q4  = lane >> 4;
  const int sub   = lane >> 3;
  const int gslot = (lane & 7) ^ sub;

  const _Float16* aSrc = Aq + (size_t)rowBase * KDIM;
  const _Float16* bSrc = Bk + (size_t)colBase * KDIM;

  auto stageHalf = [&](const _Float16* src, char* ldsbase, int kt, int h) {
    #pragma unroll
    for (int j = 0; j < 2; ++j) {
      int g = h * 16 + wid * 2 + j;
      gload_lds16(src + (size_t)(g * 8 + sub) * KDIM + kt + gslot * 8,
                  ldsbase + g * 1024);
    }
  };
  auto ld8 = [&](const char* base, int row, int s) {
    return *(const half8*)(base + row * 128 + ((s * 16) ^ ((row & 7) << 4)));
  };

  floatx4 acc[8][4];
  #pragma unroll
  for (int m = 0; m < 8; ++m)
    #pragma unroll
    for (int n = 0; n < 4; ++n)
      acc[m][n] = (floatx4)0.0f;

  stageHalf(aSrc, (char*)ldsA[0], 0, 0);
  stageHalf(aSrc, (char*)ldsA[0], 0, 1);
  stageHalf(bSrc, (char*)ldsB[0], 0, 0);
  stageHalf(bSrc, (char*)ldsB[0], 0, 1);
  stageHalf(aSrc, (char*)ldsA[1], 64, 0);
  stageHalf(aSrc, (char*)ldsA[1], 64, 1);
  stageHalf(bSrc, (char*)ldsB[1], 64, 0);
  stageHalf(bSrc, (char*)ldsB[1], 64, 1);
  asm volatile("s_waitcnt vmcnt(8)" ::: "memory");
  FULL_BAR();

  for (int t = 0; t < 8; ++t) {
    const char* bA = (const char*)ldsA[t & 1];
    const char* bB = (const char*)ldsB[t & 1];
    char* sA = (char*)ldsA[t & 1];
    char* sB = (char*)ldsB[t & 1];
    const int ktn = (t + 2) * 64;
    const bool st = (t < 6);

    half8 a[4][2], b[4][2];

    #pragma unroll
    for (int m = 0; m < 4; ++m)
      #pragma unroll
      for (int kk = 0; kk < 2; ++kk)
        a[m][kk] = ld8(bA, wm * 128 + m * 16 + l15, kk * 4 + q4);
    #pragma unroll
    for (int n = 0; n < 4; ++n)
      #pragma unroll
      for (int kk = 0; kk < 2; ++kk)
        b[n][kk] = ld8(bB, wn * 64 + n * 16 + l15, kk * 4 + q4);
    FULL_BAR();
    asm volatile("s_waitcnt lgkmcnt(0)" ::: "memory");
    __builtin_amdgcn_sched_barrier(0);
    __builtin_amdgcn_s_setprio(1);
    #pragma unroll
    for (int m = 0; m < 4; ++m)
      #pragma unroll
      for (int n = 0; n < 2; ++n)
        #pragma unroll
        for (int kk = 0; kk < 2; ++kk)
          acc[m][n] = __builtin_amdgcn_mfma_f32_16x16x32_f16(a[m][kk], b[n][kk], acc[m][n], 0, 0, 0);
    __builtin_amdgcn_s_setprio(0);
    FULL_BAR();

    if (st) stageHalf(bSrc, sB, ktn, 0);
    __builtin_amdgcn_sched_barrier(0);
    __builtin_amdgcn_s_setprio(1);
    #pragma unroll
    for (int m = 0; m < 4; ++m)
      #pragma unroll
      for (int n = 2; n < 4; ++n)
        #pragma unroll
        for (int kk = 0; kk < 2; ++kk)
          acc[m][n] = __builtin_amdgcn_mfma_f32_16x16x32_f16(a[m][kk], b[n][kk], acc[m][n], 0, 0, 0);
    __builtin_amdgcn_s_setprio(0);
    FULL_BAR();

    #pragma unroll
    for (int m = 0; m < 4; ++m)
      #pragma unroll
      for (int kk = 0; kk < 2; ++kk)
        a[m][kk] = ld8(bA, wm * 128 + (m + 4) * 16 + l15, kk * 4 + q4);
    if (st) stageHalf(bSrc, sB, ktn, 1);
    FULL_BAR();
    asm volatile("s_waitcnt lgkmcnt(0)" ::: "memory");
    __builtin_amdgcn_sched_barrier(0);
    __builtin_amdgcn_s_setprio(1);
    #pragma unroll
    for (int m = 0; m < 4; ++m)
      #pragma unroll
      for (int n = 0; n < 2; ++n)
        #pragma unroll
        for (int kk = 0; kk < 2; ++kk)
          acc[m + 4][n] = __builtin_amdgcn_mfma_f32_16x16x32_f16(a[m][kk], b[n][kk], acc[m + 4][n], 0, 0, 0);
    __builtin_amdgcn_s_setprio(0);
    FULL_BAR();

    if (st) { stageHalf(aSrc, sA, ktn, 0); stageHalf(aSrc, sA, ktn, 1); }
    __builtin_amdgcn_sched_barrier(0);
    __builtin_amdgcn_s_setprio(1);
    #pragma unroll
    for (int m = 0; m < 4; ++m)
      #pragma unroll
      for (int n = 2; n < 4; ++n)
        #pragma unroll
        for (int kk = 0; kk < 2; ++kk)
          acc[m + 4][n] = __builtin_amdgcn_mfma_f32_16x16x32_f16(a[m][kk], b[n][kk], acc[m + 4][n], 0, 0, 0);
    __builtin_amdgcn_s_setprio(0);
    __builtin_amdgcn_sched_barrier(0);
    if (t < 6)      asm volatile("s_waitcnt vmcnt(8)" ::: "memory");
    else if (t == 6) asm volatile("s_waitcnt vmcnt(0)" ::: "memory");
    FULL_BAR();
  }

  #pragma unroll
  for (int m = 0; m < 8; ++m) {
    #pragma unroll
    for (int n = 0; n < 4; ++n) {
      int col = colBase + wn * 64 + n * 16 + l15;
      #pragma unroll
      for (int r = 0; r < 4; ++r) {
        int row = rowBase + wm * 128 + m * 16 + q4 * 4 + r;
        outp[(size_t)row * NKEYS + col] = acc[m][n][r];
      }
    }
  }
}

// ---------------- top-16 + scatter-softmax gates (radix-select) ----------------
__global__ __launch_bounds__(256) void topk_gates_kernel(const float* __restrict__ scores,
                                                         float* __restrict__ gates) {
  __shared__ uint32_t hist[4096];
  __shared__ uint32_t sA[256];
  __shared__ uint32_t av[16], ai[16];
  __shared__ uint32_t sk[KTOP], si[KTOP];
  __shared__ uint32_t cntA, cntC;
  __shared__ int s_p; __shared__ uint32_t s_above;
  __shared__ float gk[KTOP]; __shared__ float s_gother;

  const int tid  = threadIdx.x;
  const int lane = tid & 63;
  const int w    = tid >> 6;
  const float* srow = scores + (size_t)blockIdx.x * NKEYS;

  uint4 z4 = {0, 0, 0, 0};
  #pragma unroll
  for (int i = 0; i < 4; ++i) ((uint4*)hist)[tid + 256 * i] = z4;
  if (tid == 0) { cntA = 0; cntC = 0; }

  uint32_t key[16];
  const int base = (w << 10) + (lane << 4);
  {
    const float4* p4 = (const float4*)(srow + base);
    #pragma unroll
    for (int i = 0; i < 4; ++i) {
      float4 t = p4[i];
      float tv[4] = { t.x, t.y, t.z, t.w };
      #pragma unroll
      for (int c = 0; c < 4; ++c) {
        uint32_t u = __float_as_uint(tv[c]);
        key[i * 4 + c] = u ^ (uint32_t)(((int32_t)u >> 31) | 0x80000000);
      }
    }
  }
  __syncthreads();

  #pragma unroll
  for (int j = 0; j < 16; ++j) atomicAdd(&hist[key[j] >> 20], 1u);
  __syncthreads();

  uint32_t h[16];
  #pragma unroll
  for (int i = 0; i < 16; ++i) h[i] = hist[tid * 16 + i];
  uint32_t sfx[17]; sfx[16] = 0;
  #pragma unroll
  for (int i = 15; i >= 0; --i) sfx[i] = sfx[i + 1] + h[i];
  sA[tid] = sfx[0];
  __syncthreads();
  uint32_t s = sfx[0];
  #pragma unroll
  for (int off = 1; off < 256; off <<= 1) {
    uint32_t add = (tid + off < 256) ? sA[tid + off] : 0;
    __syncthreads();
    s += add; sA[tid] = s;
    __syncthreads();
  }
  const uint32_t exclHi = s - sfx[0];

  #pragma unroll
  for (int i = 0; i < 16; ++i) {
    uint32_t cg = exclHi + sfx[i + 1];
    if (cg < KTOP && cg + h[i] >= KTOP) { s_p = tid * 16 + i; s_above = cg; }
  }
  __syncthreads();
  const uint32_t p = (uint32_t)s_p;
  const uint32_t above = s_above;
  const uint32_t need = KTOP - above;

  uint32_t* ck = hist;
  uint32_t* ci = hist + 2048;
  #pragma unroll
  for (int j = 0; j < 16; ++j) {
    uint32_t b = key[j] >> 20;
    if (b >= p) {
      uint32_t idx = (uint32_t)(base + j);
      if (b > p) { uint32_t pos = atomicAdd(&cntA, 1u); av[pos] = key[j]; ai[pos] = idx; }
      else       { uint32_t pos = atomicAdd(&cntC, 1u); if (pos < 2048u) { ck[pos] = key[j]; ci[pos] = idx; } }
    }
  }
  __syncthreads();

  const uint32_t nA = cntA;
  if (tid < nA) { sk[tid] = av[tid]; si[tid] = ai[tid]; }

  if (w == 0) {
    const uint32_t nC = min(cntC, 2048u);
    for (uint32_t k = 0; k < need; ++k) {
      uint32_t bk = 0, bi = 0xFFFFFFFFu, bp = 0;
      for (uint32_t c = lane; c < nC; c += 64) {
        uint32_t kk = ck[c], ii = ci[c];
        if (kk > bk || (kk == bk && ii < bi)) { bk = kk; bi = ii; bp = c; }
      }
      #pragma unroll
      for (int off = 32; off >= 1; off >>= 1) {
        uint32_t ok = __shfl_down(bk, off);
        uint32_t oi = __shfl_down(bi, off);
        uint32_t op = __shfl_down(bp, off);
        if (ok > bk || (ok == bk && oi < bi)) { bk = ok; bi = oi; bp = op; }
      }
      bp = __shfl(bp, 0);
      if (lane == 0) { ck[bp] = 0; sk[nA + k] = bk; si[nA + k] = bi; }
    }
  }
  __syncthreads();

  if (tid == 0) {
    float f[KTOP]; float mx = 0.f;
    #pragma unroll
    for (int k = 0; k < KTOP; ++k) {
      uint32_t kk = sk[k];
      float fv = (kk & 0x80000000u) ? __uint_as_float(kk ^ 0x80000000u)
                                    : __uint_as_float(~kk);
      f[k] = fv; mx = fmaxf(mx, fv);
    }
    float eo = __expf(-mx);
    float Z = (float)(NKEYS - KTOP) * eo;
    float e[KTOP];
    #pragma unroll
    for (int k = 0; k < KTOP; ++k) { e[k] = __expf(f[k] - mx); Z += e[k]; }
    float inv = 1.f / Z;
    #pragma unroll
    for (int k = 0; k < KTOP; ++k) gk[k] = e[k] * inv;
    s_gother = eo * inv;
  }
  __syncthreads();

  float go = s_gother;
  floatx4 g4 = { go, go, go, go };
  float* grow = gates + (size_t)blockIdx.x * NKEYS;
  #pragma unroll
  for (int j = 0; j < 4; ++j)
    __builtin_nontemporal_store(g4, (floatx4*)grow + j * 256 + tid);
  __syncthreads();
  if (tid < KTOP) grow[si[tid]] = gk[tid];
}

extern "C" void kernel_launch(void* const* d_in, const int* in_sizes, int n_in,
                              void* d_out, int out_size, void* d_ws, size_t ws_size,
                              hipStream_t stream) {
  const float* x    = (const float*)d_in[0];
  const float* keys = (const float*)d_in[1];
  const float* W    = (const float*)d_in[2];
  const float* bias = (const float*)d_in[3];
  (void)in_sizes; (void)n_in; (void)out_size; (void)ws_size;

  float* gates  = (float*)d_out;
  float* scores = (float*)d_out + (size_t)BS_T * NKEYS;

  _Float16* W_h = (_Float16*)d_ws;                 // 4 MB
  _Float16* k_h = W_h + (size_t)KDIM * XDIM;       // 4 MB
  _Float16* q_h = k_h + (size_t)NKEYS * KDIM;      // 16 MB

  cvt_f32_f16_v<<<dim3(1024), dim3(256), 0, stream>>>(W, W_h, KDIM * XDIM / 8);
  cvt_f32_f16_v<<<dim3(1024), dim3(256), 0, stream>>>(keys, k_h, NKEYS * KDIM / 8);

  // query = x @ W^T + b -> q_h (fp16). v11: k-rotation + contiguous-A, grid 256
  gemm1_pipe<<<dim3(BS_T / 64), dim3(512), 0, stream>>>(x, W_h, bias, q_h);

  // scores = q @ keys^T -> fp32. 256x256, counted-vmcnt pipe, grid 1024
  gemm2_pipe<<<dim3((BS_T / 256) * (NKEYS / 256)), dim3(512), 0, stream>>>(
      q_h, k_h, scores);

  topk_gates_kernel<<<dim3(BS_T), dim3(256), 0, stream>>>(scores, gates);
}

// Round 22
// 324.355 us; speedup vs baseline: 1.0375x; 1.0225x over previous
//
#include <hip/hip_runtime.h>
#include <stdint.h>

#define BS_T   16384
#define XDIM   4096
#define KDIM   512
#define NKEYS  4096
#define KTOP   16

typedef _Float16 half8  __attribute__((ext_vector_type(8)));
typedef _Float16 half4  __attribute__((ext_vector_type(4)));
typedef float    floatx4 __attribute__((ext_vector_type(4)));

// async global->LDS, 16B per lane; LDS dest is wave-uniform base + lane*16
__device__ static inline void gload_lds16(const void* g, void* l) {
  __builtin_amdgcn_global_load_lds(
      (const __attribute__((address_space(1))) uint32_t*)(uintptr_t)g,
      (__attribute__((address_space(3))) uint32_t*)(uint32_t)(uintptr_t)l,
      16, 0, 0);
}

#define SBAR() __builtin_amdgcn_sched_barrier(0)
#define FULL_BAR() do { __builtin_amdgcn_sched_barrier(0); \
                        __builtin_amdgcn_s_barrier(); \
                        __builtin_amdgcn_sched_barrier(0); } while (0)

// ---------------- fp32 -> fp16 convert (vectorized, grid-stride) ----------------
__global__ __launch_bounds__(256) void cvt_f32_f16_v(const float* __restrict__ in,
                                                     _Float16* __restrict__ out, int n8) {
  int stride = gridDim.x * 256;
  for (int i = blockIdx.x * 256 + threadIdx.x; i < n8; i += stride) {
    float4 v0 = ((const float4*)in)[2 * i];
    float4 v1 = ((const float4*)in)[2 * i + 1];
    half8 h = { (_Float16)v0.x, (_Float16)v0.y, (_Float16)v0.z, (_Float16)v0.w,
                (_Float16)v1.x, (_Float16)v1.y, (_Float16)v1.z, (_Float16)v1.w };
    ((half8*)out)[i] = h;
  }
}

// ---------------- GEMM1 v11 (k-rotation + contiguous-A; best measured) -----------
__global__ __launch_bounds__(512, 1)
void gemm1_pipe(const float* __restrict__ X, const _Float16* __restrict__ Wh,
                const float* __restrict__ bias, _Float16* __restrict__ Q) {
  __shared__ __align__(16) _Float16 ldsA[2][64 * 64];    // 2 x 8 KB
  __shared__ __align__(16) _Float16 ldsB[2][512 * 64];   // 2 x 64 KB

  const int tid  = threadIdx.x;
  const int lane = tid & 63;
  const int wid  = tid >> 6;            // 0..7
  const int rowBase = blockIdx.x * 64;
  const int rot  = (blockIdx.x * 29) & 63;   // bijective k-tile rotation
  const int wc  = wid * 64;
  const int l15 = lane & 15;
  const int q4  = lane >> 4;
  const int sub   = lane >> 3;
  const int gslot = (lane & 7) ^ sub;

  auto KT = [&](int t) { return ((t + rot) & 63) * 64; };

  // A staging remap: f = tid + j*512; row = f>>4; 16B slot s = f&15 (row-contig)
  const int r0 = tid >> 4,          s0 = tid & 15;
  const int r1 = (tid + 512) >> 4,  s1 = (tid + 512) & 15;
  const float* aSrc0 = X + (size_t)(rowBase + r0) * XDIM + s0 * 4;
  const float* aSrc1 = X + (size_t)(rowBase + r1) * XDIM + s1 * 4;
  const int aoff0 = r0 * 128 + (((s0 >> 1) * 16) ^ ((r0 & 7) << 4)) + (s0 & 1) * 8;
  const int aoff1 = r1 * 128 + (((s1 >> 1) * 16) ^ ((r1 & 7) << 4)) + (s1 & 1) * 8;

  const _Float16* const bSrc = Wh + (size_t)(wc + sub) * XDIM + gslot * 8;

  auto stageB = [&](int kt, int buf) {
    char* bd = (char*)&ldsB[buf][0] + wid * 8192;
    #pragma unroll
    for (int i = 0; i < 8; ++i)
      gload_lds16(bSrc + (size_t)i * 8 * XDIM + kt, bd + i * 1024);
  };
  auto writeA = [&](int buf, float4 v0, float4 v1) {
    half4 h0 = { (_Float16)v0.x, (_Float16)v0.y, (_Float16)v0.z, (_Float16)v0.w };
    half4 h1 = { (_Float16)v1.x, (_Float16)v1.y, (_Float16)v1.z, (_Float16)v1.w };
    *(half4*)((char*)&ldsA[buf][0] + aoff0) = h0;
    *(half4*)((char*)&ldsA[buf][0] + aoff1) = h1;
  };
  auto ld8 = [&](const char* base, int row, int s) {
    return *(const half8*)(base + row * 128 + ((s * 16) ^ ((row & 7) << 4)));
  };

  floatx4 acc[4][4];
  #pragma unroll
  for (int m = 0; m < 4; ++m)
    #pragma unroll
    for (int n = 0; n < 4; ++n)
      acc[m][n] = (floatx4)0.0f;

  // ---- prologue (k-tiles KT(0), KT(1)) ----
  float4 p0  = *(const float4*)(aSrc0 + KT(0));
  float4 p1  = *(const float4*)(aSrc1 + KT(0));
  float4 aw0 = *(const float4*)(aSrc0 + KT(1));
  float4 aw1 = *(const float4*)(aSrc1 + KT(1));
  stageB(KT(0), 0);
  stageB(KT(1), 1);
  writeA(0, p0, p1);                                    // compiler waits p loads
  asm volatile("s_waitcnt lgkmcnt(0)" ::: "memory");
  asm volatile("s_waitcnt vmcnt(8)" ::: "memory");      // drain aw + B(0); B(1) flies
  FULL_BAR();

  #pragma unroll 2
  for (int t = 0; t < 64; ++t) {
    const int cu = t & 1;
    const char* bA = (const char*)&ldsA[cu][0];
    const char* bB = (const char*)&ldsB[cu][0];

    half8 a[4][2], b[4][2];
    #pragma unroll
    for (int m = 0; m < 4; ++m)
      #pragma unroll
      for (int kk = 0; kk < 2; ++kk)
        a[m][kk] = ld8(bA, m * 16 + l15, kk * 4 + q4);
    #pragma unroll
    for (int n = 0; n < 4; ++n)
      #pragma unroll
      for (int kk = 0; kk < 2; ++kk)
        b[n][kk] = ld8(bB, wc + n * 16 + l15, kk * 4 + q4);
    float4 nl0, nl1;
    if (t < 62) {
      nl0 = *(const float4*)(aSrc0 + KT(t + 2));
      nl1 = *(const float4*)(aSrc1 + KT(t + 2));
    }
    asm volatile("s_waitcnt lgkmcnt(0)" ::: "memory");
    __builtin_amdgcn_sched_barrier(0);
    if (t < 62) stageB(KT(t + 2), cu);
    __builtin_amdgcn_sched_barrier(0);

    __builtin_amdgcn_s_setprio(1);
    #pragma unroll
    for (int m = 0; m < 4; ++m)
      #pragma unroll
      for (int n = 0; n < 4; ++n)
        #pragma unroll
        for (int kk = 0; kk < 2; ++kk)
          acc[m][n] = __builtin_amdgcn_mfma_f32_16x16x32_f16(a[m][kk], b[n][kk], acc[m][n], 0, 0, 0);
    __builtin_amdgcn_s_setprio(0);

    if (t < 63) writeA(cu ^ 1, aw0, aw1);
    asm volatile("s_waitcnt lgkmcnt(0)" ::: "memory");
    __builtin_amdgcn_sched_barrier(0);
    if (t < 62)       asm volatile("s_waitcnt vmcnt(10)" ::: "memory");
    else if (t == 62) asm volatile("s_waitcnt vmcnt(0)"  ::: "memory");
    FULL_BAR();
    aw0 = nl0; aw1 = nl1;
  }

  // epilogue
  #pragma unroll
  for (int m = 0; m < 4; ++m) {
    #pragma unroll
    for (int n = 0; n < 4; ++n) {
      int col = wc + n * 16 + l15;
      float bv = bias[col];
      #pragma unroll
      for (int r = 0; r < 4; ++r) {
        int row = rowBase + m * 16 + q4 * 4 + r;
        Q[(size_t)row * KDIM + col] = (_Float16)(acc[m][n][r] + bv);
      }
    }
  }
}

// ---------------- GEMM2 v2: 128x128 tile, 2 blocks/CU, counted-vmcnt 2-barrier ----
// Combination never tested for g2: 2 blk/CU (sibling fills barrier drains, m114)
// AND counted vmcnt (loads stay in flight across barriers). 4 waves (2x2, 64x64
// wave-tile), BK=64, 8 K-tiles, LDS 64 KB. Per tile: reads -> lgkm0 -> BAR ->
// stage(t+2) same buf -> 32 MFMA -> vmcnt(8) [retires own stage(t+1)] -> BAR.
// Each wave gates its own loads pre-barrier => all stages landed post-barrier.
__global__ __launch_bounds__(256, 2)
void gemm2_pipe(const _Float16* __restrict__ Aq, const _Float16* __restrict__ Bk,
                float* __restrict__ outp) {
  __shared__ __align__(16) _Float16 ldsA[2][128 * 64];   // 2 x 16 KB
  __shared__ __align__(16) _Float16 ldsB[2][128 * 64];   // 2 x 16 KB

  const int tid  = threadIdx.x;
  const int lane = tid & 63;
  const int wid  = tid >> 6;            // 0..3
  const int bid  = blockIdx.x;
  const int nCol = NKEYS / 128;         // 32
  const int rowBase = (bid / nCol) * 128;
  const int colBase = (bid % nCol) * 128;
  const int wm = wid >> 1;              // 0..1
  const int wn = wid & 1;               // 0..1
  const int l15 = lane & 15;
  const int q4  = lane >> 4;
  const int sub   = lane >> 3;
  const int gslot = (lane & 7) ^ sub;

  const _Float16* aSrc = Aq + (size_t)rowBase * KDIM;
  const _Float16* bSrc = Bk + (size_t)colBase * KDIM;

  // staging: 16 A groups + 16 B groups (8 rows x 1KB each); wave stages 4 of each
  auto stage = [&](int kt, int buf) {
    char* la = (char*)&ldsA[buf][0];
    char* lb = (char*)&ldsB[buf][0];
    #pragma unroll
    for (int j = 0; j < 4; ++j) {
      int g = wid * 4 + j;
      gload_lds16(aSrc + (size_t)(g * 8 + sub) * KDIM + kt + gslot * 8, la + g * 1024);
      gload_lds16(bSrc + (size_t)(g * 8 + sub) * KDIM + kt + gslot * 8, lb + g * 1024);
    }
  };
  auto ld8 = [&](const char* base, int row, int s) {
    return *(const half8*)(base + row * 128 + ((s * 16) ^ ((row & 7) << 4)));
  };

  floatx4 acc[4][4];
  #pragma unroll
  for (int m = 0; m < 4; ++m)
    #pragma unroll
    for (int n = 0; n < 4; ++n)
      acc[m][n] = (floatx4)0.0f;

  // prologue: K-tiles 0,1 staged; own stage(0) retired (8 own loads), stage(1) flies
  stage(0, 0);
  stage(64, 1);
  asm volatile("s_waitcnt vmcnt(8)" ::: "memory");
  FULL_BAR();

  for (int t = 0; t < 8; ++t) {
    const int cu = t & 1;
    const char* bA = (const char*)&ldsA[cu][0];
    const char* bB = (const char*)&ldsB[cu][0];

    half8 a[4][2], b[4][2];
    #pragma unroll
    for (int m = 0; m < 4; ++m)
      #pragma unroll
      for (int kk = 0; kk < 2; ++kk)
        a[m][kk] = ld8(bA, wm * 64 + m * 16 + l15, kk * 4 + q4);
    #pragma unroll
    for (int n = 0; n < 4; ++n)
      #pragma unroll
      for (int kk = 0; kk < 2; ++kk)
        b[n][kk] = ld8(bB, wn * 64 + n * 16 + l15, kk * 4 + q4);
    asm volatile("s_waitcnt lgkmcnt(0)" ::: "memory");
    FULL_BAR();                          // all waves done reading buf[cu]

    if (t < 6) stage((t + 2) * 64, cu);  // overwrite just-read buffer
    __builtin_amdgcn_sched_barrier(0);

    __builtin_amdgcn_s_setprio(1);
    #pragma unroll
    for (int m = 0; m < 4; ++m)
      #pragma unroll
      for (int n = 0; n < 4; ++n)
        #pragma unroll
        for (int kk = 0; kk < 2; ++kk)
          acc[m][n] = __builtin_amdgcn_mfma_f32_16x16x32_f16(a[m][kk], b[n][kk], acc[m][n], 0, 0, 0);
    __builtin_amdgcn_s_setprio(0);
    __builtin_amdgcn_sched_barrier(0);

    if (t < 6)      asm volatile("s_waitcnt vmcnt(8)" ::: "memory");  // own stage(t+1)
    else if (t == 6) asm volatile("s_waitcnt vmcnt(0)" ::: "memory");
    FULL_BAR();
  }

  // epilogue: direct C-store (R19-proven)
  #pragma unroll
  for (int m = 0; m < 4; ++m) {
    #pragma unroll
    for (int n = 0; n < 4; ++n) {
      int col = colBase + wn * 64 + n * 16 + l15;
      #pragma unroll
      for (int r = 0; r < 4; ++r) {
        int row = rowBase + wm * 64 + m * 16 + q4 * 4 + r;
        outp[(size_t)row * NKEYS + col] = acc[m][n][r];
      }
    }
  }
}

// ---------------- top-16 + scatter-softmax gates (radix-select) ----------------
__global__ __launch_bounds__(256) void topk_gates_kernel(const float* __restrict__ scores,
                                                         float* __restrict__ gates) {
  __shared__ uint32_t hist[4096];
  __shared__ uint32_t sA[256];
  __shared__ uint32_t av[16], ai[16];
  __shared__ uint32_t sk[KTOP], si[KTOP];
  __shared__ uint32_t cntA, cntC;
  __shared__ int s_p; __shared__ uint32_t s_above;
  __shared__ float gk[KTOP]; __shared__ float s_gother;

  const int tid  = threadIdx.x;
  const int lane = tid & 63;
  const int w    = tid >> 6;
  const float* srow = scores + (size_t)blockIdx.x * NKEYS;

  uint4 z4 = {0, 0, 0, 0};
  #pragma unroll
  for (int i = 0; i < 4; ++i) ((uint4*)hist)[tid + 256 * i] = z4;
  if (tid == 0) { cntA = 0; cntC = 0; }

  uint32_t key[16];
  const int base = (w << 10) + (lane << 4);
  {
    const float4* p4 = (const float4*)(srow + base);
    #pragma unroll
    for (int i = 0; i < 4; ++i) {
      float4 t = p4[i];
      float tv[4] = { t.x, t.y, t.z, t.w };
      #pragma unroll
      for (int c = 0; c < 4; ++c) {
        uint32_t u = __float_as_uint(tv[c]);
        key[i * 4 + c] = u ^ (uint32_t)(((int32_t)u >> 31) | 0x80000000);
      }
    }
  }
  __syncthreads();

  #pragma unroll
  for (int j = 0; j < 16; ++j) atomicAdd(&hist[key[j] >> 20], 1u);
  __syncthreads();

  uint32_t h[16];
  #pragma unroll
  for (int i = 0; i < 16; ++i) h[i] = hist[tid * 16 + i];
  uint32_t sfx[17]; sfx[16] = 0;
  #pragma unroll
  for (int i = 15; i >= 0; --i) sfx[i] = sfx[i + 1] + h[i];
  sA[tid] = sfx[0];
  __syncthreads();
  uint32_t s = sfx[0];
  #pragma unroll
  for (int off = 1; off < 256; off <<= 1) {
    uint32_t add = (tid + off < 256) ? sA[tid + off] : 0;
    __syncthreads();
    s += add; sA[tid] = s;
    __syncthreads();
  }
  const uint32_t exclHi = s - sfx[0];

  #pragma unroll
  for (int i = 0; i < 16; ++i) {
    uint32_t cg = exclHi + sfx[i + 1];
    if (cg < KTOP && cg + h[i] >= KTOP) { s_p = tid * 16 + i; s_above = cg; }
  }
  __syncthreads();
  const uint32_t p = (uint32_t)s_p;
  const uint32_t above = s_above;
  const uint32_t need = KTOP - above;

  uint32_t* ck = hist;
  uint32_t* ci = hist + 2048;
  #pragma unroll
  for (int j = 0; j < 16; ++j) {
    uint32_t b = key[j] >> 20;
    if (b >= p) {
      uint32_t idx = (uint32_t)(base + j);
      if (b > p) { uint32_t pos = atomicAdd(&cntA, 1u); av[pos] = key[j]; ai[pos] = idx; }
      else       { uint32_t pos = atomicAdd(&cntC, 1u); if (pos < 2048u) { ck[pos] = key[j]; ci[pos] = idx; } }
    }
  }
  __syncthreads();

  const uint32_t nA = cntA;
  if (tid < nA) { sk[tid] = av[tid]; si[tid] = ai[tid]; }

  if (w == 0) {
    const uint32_t nC = min(cntC, 2048u);
    for (uint32_t k = 0; k < need; ++k) {
      uint32_t bk = 0, bi = 0xFFFFFFFFu, bp = 0;
      for (uint32_t c = lane; c < nC; c += 64) {
        uint32_t kk = ck[c], ii = ci[c];
        if (kk > bk || (kk == bk && ii < bi)) { bk = kk; bi = ii; bp = c; }
      }
      #pragma unroll
      for (int off = 32; off >= 1; off >>= 1) {
        uint32_t ok = __shfl_down(bk, off);
        uint32_t oi = __shfl_down(bi, off);
        uint32_t op = __shfl_down(bp, off);
        if (ok > bk || (ok == bk && oi < bi)) { bk = ok; bi = oi; bp = op; }
      }
      bp = __shfl(bp, 0);
      if (lane == 0) { ck[bp] = 0; sk[nA + k] = bk; si[nA + k] = bi; }
    }
  }
  __syncthreads();

  if (tid == 0) {
    float f[KTOP]; float mx = 0.f;
    #pragma unroll
    for (int k = 0; k < KTOP; ++k) {
      uint32_t kk = sk[k];
      float fv = (kk & 0x80000000u) ? __uint_as_float(kk ^ 0x80000000u)
                                    : __uint_as_float(~kk);
      f[k] = fv; mx = fmaxf(mx, fv);
    }
    float eo = __expf(-mx);
    float Z = (float)(NKEYS - KTOP) * eo;
    float e[KTOP];
    #pragma unroll
    for (int k = 0; k < KTOP; ++k) { e[k] = __expf(f[k] - mx); Z += e[k]; }
    float inv = 1.f / Z;
    #pragma unroll
    for (int k = 0; k < KTOP; ++k) gk[k] = e[k] * inv;
    s_gother = eo * inv;
  }
  __syncthreads();

  float go = s_gother;
  floatx4 g4 = { go, go, go, go };
  float* grow = gates + (size_t)blockIdx.x * NKEYS;
  #pragma unroll
  for (int j = 0; j < 4; ++j)
    __builtin_nontemporal_store(g4, (floatx4*)grow + j * 256 + tid);
  __syncthreads();
  if (tid < KTOP) grow[si[tid]] = gk[tid];
}

extern "C" void kernel_launch(void* const* d_in, const int* in_sizes, int n_in,
                              void* d_out, int out_size, void* d_ws, size_t ws_size,
                              hipStream_t stream) {
  const float* x    = (const float*)d_in[0];
  const float* keys = (const float*)d_in[1];
  const float* W    = (const float*)d_in[2];
  const float* bias = (const float*)d_in[3];
  (void)in_sizes; (void)n_in; (void)out_size; (void)ws_size;

  float* gates  = (float*)d_out;
  float* scores = (float*)d_out + (size_t)BS_T * NKEYS;

  _Float16* W_h = (_Float16*)d_ws;                 // 4 MB
  _Float16* k_h = W_h + (size_t)KDIM * XDIM;       // 4 MB
  _Float16* q_h = k_h + (size_t)NKEYS * KDIM;      // 16 MB

  cvt_f32_f16_v<<<dim3(1024), dim3(256), 0, stream>>>(W, W_h, KDIM * XDIM / 8);
  cvt_f32_f16_v<<<dim3(1024), dim3(256), 0, stream>>>(keys, k_h, NKEYS * KDIM / 8);

  // query = x @ W^T + b -> q_h (fp16). v11: k-rotation + contiguous-A, grid 256
  gemm1_pipe<<<dim3(BS_T / 64), dim3(512), 0, stream>>>(x, W_h, bias, q_h);

  // scores = q @ keys^T -> fp32. 128x128, 2 blk/CU, counted-vmcnt 2-barrier
  gemm2_pipe<<<dim3((BS_T / 128) * (NKEYS / 128)), dim3(256), 0, stream>>>(
      q_h, k_h, scores);

  topk_gates_kernel<<<dim3(BS_T), dim3(256), 0, stream>>>(scores, gates);
}